// Round 1
// baseline (1150.310 us; speedup 1.0000x reference)
//
#include <hip/hip_runtime.h>

typedef unsigned short u16;
typedef unsigned int u32;
typedef float f32x4 __attribute__((ext_vector_type(4)));
typedef __bf16 bf16x8 __attribute__((ext_vector_type(8)));

#define F 256
#define T_OUT 8
#define N_MONO 150000
#define N_CLEAV 100000
#define N_FRAG 80000
#define N_OUT 40000
#define M_CLEAV_PAD 100096   // 782 * 128

static __device__ __forceinline__ u16 f2bf(float f) {
  u32 u = __float_as_uint(f);
  u32 r = (u + 0x7FFFu + ((u >> 16) & 1u)) >> 16;
  return (u16)r;
}
static __device__ __forceinline__ float bf2f(u16 b) {
  return __uint_as_float(((u32)b) << 16);
}
static __device__ __forceinline__ float sigmoidf(float x) {
  x = fminf(fmaxf(x, -30.f), 30.f);
  return 1.0f / (1.0f + __expf(-x));
}
static __device__ __forceinline__ float fast_tanh(float x) {
  x = fminf(fmaxf(x, -15.f), 15.f);
  float e = __expf(2.f * x);
  return (e - 1.f) / (e + 1.f);
}
static __device__ __forceinline__ void async_copy16(const u16* g, const u16* l) {
  __builtin_amdgcn_global_load_lds(
      (const __attribute__((address_space(1))) u32*)g,
      (__attribute__((address_space(3))) u32*)l,
      16, 0, 0);
}

// ---------------- K0: weight cast + bias sum ----------------
__global__ __launch_bounds__(256) void prep_kernel(
    const float* __restrict__ Wih, const float* __restrict__ Whh,
    const float* __restrict__ bih, const float* __restrict__ bhh,
    u16* __restrict__ Wihb, u16* __restrict__ Whhb, float* __restrict__ bias) {
  int i = blockIdx.x * 256 + threadIdx.x;
  if (i < 1024 * 512) Wihb[i] = f2bf(Wih[i]);
  if (i < 1024 * 256) Whhb[i] = f2bf(Whh[i]);
  if (i < 1024) bias[i] = bih[i] + bhh[i];
}

// ---------------- K1: attention pulls -> cleav [N_CLEAV, 512] bf16 --------
// one wave per cleavage node; lane holds feature slots [4*lane .. 4*lane+3]
__global__ __launch_bounds__(256) void attn_pull(
    const float* __restrict__ feat, const float* __restrict__ WgL,
    const float* __restrict__ WgR, const int* __restrict__ lostS,
    const int* __restrict__ retS, u16* __restrict__ cleav) {
  int wave = threadIdx.x >> 6, lane = threadIdx.x & 63;
  int n = blockIdx.x * 4 + wave;
  if (n >= N_CLEAV) return;
  const float4 wgl = *(const float4*)(WgL + lane * 4);
  const float4 wgr = *(const float4*)(WgR + lane * 4);
  for (int sg = 0; sg < 2; ++sg) {
    const int* src = sg ? retS : lostS;
    float4 wg = sg ? wgr : wgl;
    float4 x[4];
    float logit[4];
#pragma unroll
    for (int d = 0; d < 4; ++d) {
      int r = src[n * 4 + d];
      x[d] = *(const float4*)(feat + (size_t)r * F + lane * 4);
      float p = x[d].x * wg.x + x[d].y * wg.y + x[d].z * wg.z + x[d].w * wg.w;
#pragma unroll
      for (int off = 32; off; off >>= 1) p += __shfl_xor(p, off);
      logit[d] = p;
    }
    float mx = fmaxf(fmaxf(logit[0], logit[1]), fmaxf(logit[2], logit[3]));
    float e0 = __expf(logit[0] - mx), e1 = __expf(logit[1] - mx);
    float e2 = __expf(logit[2] - mx), e3 = __expf(logit[3] - mx);
    float inv = 1.f / (e0 + e1 + e2 + e3);
    float a0 = e0 * inv, a1 = e1 * inv, a2 = e2 * inv, a3 = e3 * inv;
    float4 acc;
    acc.x = a0 * x[0].x + a1 * x[1].x + a2 * x[2].x + a3 * x[3].x;
    acc.y = a0 * x[0].y + a1 * x[1].y + a2 * x[2].y + a3 * x[3].y;
    acc.z = a0 * x[0].z + a1 * x[1].z + a2 * x[2].z + a3 * x[3].z;
    acc.w = a0 * x[0].w + a1 * x[1].w + a2 * x[2].w + a3 * x[3].w;
    u32 lo = (u32)f2bf(acc.x) | ((u32)f2bf(acc.y) << 16);
    u32 hi = (u32)f2bf(acc.z) | ((u32)f2bf(acc.w) << 16);
    *(uint2*)(cleav + (size_t)n * 512 + sg * 256 + lane * 4) = make_uint2(lo, hi);
  }
}

// ---------------- GEMM: C[M,1024] = A[M,K] * B[1024,K]^T (+epilogue) ------
// bf16 MFMA 16x16x32, 128x128 tile, BK=64, XOR-swizzled LDS, global_load_lds.
// EPI==0: C = acc + bias[n]  (bf16 out)
// EPI==1: C = acc + P[join[2m+1]][n]  (bf16 out)
template <int EPI, int K>
__global__ __launch_bounds__(256) void gemm_bt(
    const u16* __restrict__ A, const u16* __restrict__ Bw,
    u16* __restrict__ C, const float* __restrict__ bias,
    const int* __restrict__ join, const u16* __restrict__ P) {
  __shared__ u16 As[128 * 64];
  __shared__ u16 Bs[128 * 64];
  const int tid = threadIdx.x;
  const int lane = tid & 63;
  const int wave = tid >> 6;
  const int quad = lane >> 4;
  const int l16 = lane & 15;
  const int m0 = blockIdx.x * 128;
  const int n0 = blockIdx.y * 128;
  const int wm = (wave & 1) * 64;
  const int wn = (wave >> 1) * 64;

  f32x4 acc[4][4];
#pragma unroll
  for (int i = 0; i < 4; i++)
#pragma unroll
    for (int j = 0; j < 4; j++) acc[i][j] = (f32x4){0.f, 0.f, 0.f, 0.f};

  // staging: chunk c = jj*256+tid ; row=c>>3 ; phys j = c&7 ; logical k-blk = (c&7)^(row&7)
  int srow[4], skoff[4], ldsoff[4];
#pragma unroll
  for (int jj = 0; jj < 4; jj++) {
    int c = jj * 256 + tid;
    srow[jj] = c >> 3;
    skoff[jj] = (((c & 7) ^ ((c >> 3) & 7)) * 8);
    ldsoff[jj] = (jj * 256 + (tid & ~63)) * 8;  // u16 elements; lane*8 added by HW
  }
  const u16* Abase = A + (size_t)m0 * K;
  const u16* Bbase = Bw + (size_t)n0 * K;

  for (int k0 = 0; k0 < K; k0 += 64) {
#pragma unroll
    for (int jj = 0; jj < 4; jj++)
      async_copy16(Abase + (size_t)srow[jj] * K + k0 + skoff[jj], As + ldsoff[jj]);
#pragma unroll
    for (int jj = 0; jj < 4; jj++)
      async_copy16(Bbase + (size_t)srow[jj] * K + k0 + skoff[jj], Bs + ldsoff[jj]);
    __syncthreads();
#pragma unroll
    for (int ks = 0; ks < 2; ks++) {
      bf16x8 af[4], bfr[4];
#pragma unroll
      for (int i = 0; i < 4; i++) {
        int m = wm + i * 16 + l16;
        int jp = (ks * 4 + quad) ^ (m & 7);
        af[i] = *(const bf16x8*)&As[m * 64 + jp * 8];
      }
#pragma unroll
      for (int j = 0; j < 4; j++) {
        int n = wn + j * 16 + l16;
        int jp = (ks * 4 + quad) ^ (n & 7);
        bfr[j] = *(const bf16x8*)&Bs[n * 64 + jp * 8];
      }
#pragma unroll
      for (int i = 0; i < 4; i++)
#pragma unroll
        for (int j = 0; j < 4; j++)
          acc[i][j] = __builtin_amdgcn_mfma_f32_16x16x32_bf16(af[i], bfr[j], acc[i][j], 0, 0, 0);
    }
    __syncthreads();
  }

  // epilogue: C/D layout col=lane&15, row=quad*4+reg
#pragma unroll
  for (int i = 0; i < 4; i++) {
    int mbase = m0 + wm + i * 16 + quad * 4;
#pragma unroll
    for (int j = 0; j < 4; j++) {
      int n = n0 + wn + j * 16 + l16;
      float badd = (EPI == 0) ? bias[n] : 0.f;
#pragma unroll
      for (int r = 0; r < 4; r++) {
        int m = mbase + r;
        float v = acc[i][j][r] + badd;
        if (EPI == 1) {
          int j1 = join[2 * m + 1];
          v += bf2f(P[(size_t)j1 * 1024 + n]);
        }
        C[(size_t)m * 1024 + n] = f2bf(v);
      }
    }
  }
}

// ---------------- K3: LSTM step 1 (h0=c0=0, f-gate dead) ------------------
__global__ __launch_bounds__(256) void lstm_step1(
    const u16* __restrict__ P, const int* __restrict__ join,
    u16* __restrict__ h1, float* __restrict__ c1) {
  int m = blockIdx.x, h = threadIdx.x;
  int j0 = join[2 * m];
  const u16* row = P + (size_t)j0 * 1024;
  float iv = bf2f(row[h]);
  float gv = bf2f(row[512 + h]);
  float ov = bf2f(row[768 + h]);
  float c = sigmoidf(iv) * fast_tanh(gv);
  float hv = sigmoidf(ov) * fast_tanh(c);
  h1[(size_t)m * 256 + h] = f2bf(hv);
  c1[(size_t)m * 256 + h] = c;
}

// ------- K5: LSTM step 2 + attention over {h1,h2} + output head -----------
__global__ __launch_bounds__(256) void lstm_step2_attn_out(
    const u16* __restrict__ G2, const float* __restrict__ c1,
    const u16* __restrict__ h1b, const float* __restrict__ Wg,
    const float* __restrict__ Wout, const float* __restrict__ bout,
    float* __restrict__ frag_out) {
  int m = blockIdx.x, h = threadIdx.x;
  int wave = h >> 6, lane = h & 63;
  const u16* row = G2 + (size_t)m * 1024;
  float iv = bf2f(row[h]);
  float fv = bf2f(row[256 + h]);
  float gv = bf2f(row[512 + h]);
  float ov = bf2f(row[768 + h]);
  float c1v = c1[(size_t)m * 256 + h];
  float c2 = sigmoidf(fv) * c1v + sigmoidf(iv) * fast_tanh(gv);
  float h2 = sigmoidf(ov) * fast_tanh(c2);
  float h1v = bf2f(h1b[(size_t)m * 256 + h]);
  float wg = Wg[h];
  float p1 = h1v * wg, p2 = h2 * wg;
#pragma unroll
  for (int off = 32; off; off >>= 1) {
    p1 += __shfl_down(p1, off);
    p2 += __shfl_down(p2, off);
  }
  __shared__ float s1[4], s2[4], aa[2], fragL[256];
  if (lane == 0) { s1[wave] = p1; s2[wave] = p2; }
  __syncthreads();
  if (h == 0) {
    float l1 = s1[0] + s1[1] + s1[2] + s1[3];
    float l2 = s2[0] + s2[1] + s2[2] + s2[3];
    float mx = fmaxf(l1, l2);
    float e1 = __expf(l1 - mx), e2 = __expf(l2 - mx);
    float inv = 1.f / (e1 + e2);
    aa[0] = e1 * inv;
    aa[1] = e2 * inv;
  }
  __syncthreads();
  float frag = aa[0] * h1v + aa[1] * h2;
  fragL[h] = frag;
  __syncthreads();
  // output head: wave w handles t = 2w, 2w+1
#pragma unroll
  for (int tt = 0; tt < 2; ++tt) {
    int t = wave * 2 + tt;
    float s = 0.f;
#pragma unroll
    for (int q = 0; q < 4; q++) {
      int hh = lane + q * 64;
      s += fragL[hh] * Wout[hh * 8 + t];
    }
#pragma unroll
    for (int off = 32; off; off >>= 1) s += __shfl_down(s, off);
    if (lane == 0) frag_out[(size_t)m * 8 + t] = fmaxf(s + bout[t], 0.f);
  }
}

// ---------------- K6: combine scatter-sum ---------------------------------
__global__ __launch_bounds__(256) void scatter_sum(
    const float* __restrict__ frag_out, const int* __restrict__ comb,
    float* __restrict__ out) {
  int tid = blockIdx.x * 256 + threadIdx.x;
  if (tid >= N_OUT * 8) return;
  int n = tid >> 3, t = tid & 7;
  float s = 0.f;
#pragma unroll
  for (int d = 0; d < 4; d++) {
    int f = comb[n * 4 + d];
    s += frag_out[(size_t)f * 8 + t];
  }
  out[tid] = s;
}

extern "C" void kernel_launch(void* const* d_in, const int* in_sizes, int n_in,
                              void* d_out, int out_size, void* d_ws, size_t ws_size,
                              hipStream_t stream) {
  const float* feature = (const float*)d_in[0];
  const float* WgL = (const float*)d_in[1];
  const float* WgR = (const float*)d_in[2];
  const float* Wih = (const float*)d_in[3];
  const float* Whh = (const float*)d_in[4];
  const float* bih = (const float*)d_in[5];
  const float* bhh = (const float*)d_in[6];
  const float* Wgf = (const float*)d_in[7];
  const float* Wout = (const float*)d_in[8];
  const float* bout = (const float*)d_in[9];
  const int* lostS = (const int*)d_in[10];
  const int* retS = (const int*)d_in[11];
  const int* joinS = (const int*)d_in[12];
  const int* combS = (const int*)d_in[13];
  float* out = (float*)d_out;

  char* ws = (char*)d_ws;
  size_t off = 0;
  auto alloc = [&](size_t bytes) -> char* {
    char* p = ws + off;
    off = (off + bytes + 255) & ~(size_t)255;
    return p;
  };
  u16* Wihb = (u16*)alloc((size_t)1024 * 512 * 2);
  u16* Whhb = (u16*)alloc((size_t)1024 * 256 * 2);
  float* bias = (float*)alloc(1024 * 4);
  u16* P = (u16*)alloc((size_t)M_CLEAV_PAD * 1024 * 2);
  u16* h1 = (u16*)alloc((size_t)N_FRAG * 256 * 2);
  float* c1 = (float*)alloc((size_t)N_FRAG * 256 * 4);
  float* frag_out = (float*)alloc((size_t)N_FRAG * 8 * 4);
  // union region: cleav (dead after GEMM-P) then gates2
  char* uni = alloc((size_t)N_FRAG * 1024 * 2);  // 164 MB >= cleav's 102.5 MB
  u16* cleav = (u16*)uni;
  u16* gates2 = (u16*)uni;

  prep_kernel<<<2048, 256, 0, stream>>>(Wih, Whh, bih, bhh, Wihb, Whhb, bias);
  attn_pull<<<N_CLEAV / 4, 256, 0, stream>>>(feature, WgL, WgR, lostS, retS, cleav);
  gemm_bt<0, 512><<<dim3(M_CLEAV_PAD / 128, 8), 256, 0, stream>>>(
      cleav, Wihb, P, bias, nullptr, nullptr);
  lstm_step1<<<N_FRAG, 256, 0, stream>>>(P, joinS, h1, c1);
  gemm_bt<1, 256><<<dim3(N_FRAG / 128, 8), 256, 0, stream>>>(
      h1, Whhb, gates2, nullptr, joinS, P);
  lstm_step2_attn_out<<<N_FRAG, 256, 0, stream>>>(gates2, c1, h1, Wgf, Wout, bout, frag_out);
  scatter_sum<<<(N_OUT * 8 + 255) / 256, 256, 0, stream>>>(frag_out, combS, out);
}

// Round 2
// 867.080 us; speedup vs baseline: 1.3266x; 1.3266x over previous
//
#include <hip/hip_runtime.h>

typedef unsigned short u16;
typedef unsigned int u32;
typedef float f32x4 __attribute__((ext_vector_type(4)));
typedef __bf16 bf16x8 __attribute__((ext_vector_type(8)));

#define F 256
#define T_OUT 8
#define N_MONO 150000
#define N_CLEAV 100000
#define N_FRAG 80000
#define N_OUT 40000
#define M_CLEAV_PAD 100096   // 782 * 128

static __device__ __forceinline__ u16 f2bf(float f) {
  u32 u = __float_as_uint(f);
  u32 r = (u + 0x7FFFu + ((u >> 16) & 1u)) >> 16;
  return (u16)r;
}
static __device__ __forceinline__ float bf2f(u16 b) {
  return __uint_as_float(((u32)b) << 16);
}
// clamp-free: x->-inf: e^-x->inf, rcp->0 (correct); x->+inf: e^-x->0 -> 1
static __device__ __forceinline__ float sigmoidf(float x) {
  return __frcp_rn(1.0f + __expf(-x));
}
// tanh = 1 - 2/(e^{2x}+1); 2x->+inf: e->inf, 2/inf=0 -> 1; 2x->-inf: e->0 -> -1
static __device__ __forceinline__ float fast_tanh(float x) {
  return 1.0f - 2.0f * __frcp_rn(__expf(2.0f * x) + 1.0f);
}
static __device__ __forceinline__ void async_copy16(const u16* g, const u16* l) {
  __builtin_amdgcn_global_load_lds(
      (const __attribute__((address_space(1))) u32*)g,
      (__attribute__((address_space(3))) u32*)l,
      16, 0, 0);
}

// ---------------- K0: weight cast + bias sum ----------------
__global__ __launch_bounds__(256) void prep_kernel(
    const float* __restrict__ Wih, const float* __restrict__ Whh,
    const float* __restrict__ bih, const float* __restrict__ bhh,
    u16* __restrict__ Wihb, u16* __restrict__ Whhb, float* __restrict__ bias) {
  int i = blockIdx.x * 256 + threadIdx.x;
  if (i < 1024 * 512) Wihb[i] = f2bf(Wih[i]);
  if (i < 1024 * 256) Whhb[i] = f2bf(Whh[i]);
  if (i < 1024) bias[i] = bih[i] + bhh[i];
}

// ---------------- K1: attention pulls -> cleav [N_CLEAV, 512] bf16 --------
// one wave per cleavage node; lane holds feature slots [4*lane .. 4*lane+3]
__global__ __launch_bounds__(256) void attn_pull(
    const float* __restrict__ feat, const float* __restrict__ WgL,
    const float* __restrict__ WgR, const int* __restrict__ lostS,
    const int* __restrict__ retS, u16* __restrict__ cleav) {
  int wave = threadIdx.x >> 6, lane = threadIdx.x & 63;
  int n = blockIdx.x * 4 + wave;
  if (n >= N_CLEAV) return;
  const float4 wgl = *(const float4*)(WgL + lane * 4);
  const float4 wgr = *(const float4*)(WgR + lane * 4);
  for (int sg = 0; sg < 2; ++sg) {
    const int* src = sg ? retS : lostS;
    float4 wg = sg ? wgr : wgl;
    float4 x[4];
    float logit[4];
#pragma unroll
    for (int d = 0; d < 4; ++d) {
      int r = src[n * 4 + d];
      x[d] = *(const float4*)(feat + (size_t)r * F + lane * 4);
      float p = x[d].x * wg.x + x[d].y * wg.y + x[d].z * wg.z + x[d].w * wg.w;
#pragma unroll
      for (int off = 32; off; off >>= 1) p += __shfl_xor(p, off);
      logit[d] = p;
    }
    float mx = fmaxf(fmaxf(logit[0], logit[1]), fmaxf(logit[2], logit[3]));
    float e0 = __expf(logit[0] - mx), e1 = __expf(logit[1] - mx);
    float e2 = __expf(logit[2] - mx), e3 = __expf(logit[3] - mx);
    float inv = 1.f / (e0 + e1 + e2 + e3);
    float a0 = e0 * inv, a1 = e1 * inv, a2 = e2 * inv, a3 = e3 * inv;
    float4 acc;
    acc.x = a0 * x[0].x + a1 * x[1].x + a2 * x[2].x + a3 * x[3].x;
    acc.y = a0 * x[0].y + a1 * x[1].y + a2 * x[2].y + a3 * x[3].y;
    acc.z = a0 * x[0].z + a1 * x[1].z + a2 * x[2].z + a3 * x[3].z;
    acc.w = a0 * x[0].w + a1 * x[1].w + a2 * x[2].w + a3 * x[3].w;
    u32 lo = (u32)f2bf(acc.x) | ((u32)f2bf(acc.y) << 16);
    u32 hi = (u32)f2bf(acc.z) | ((u32)f2bf(acc.w) << 16);
    *(uint2*)(cleav + (size_t)n * 512 + sg * 256 + lane * 4) = make_uint2(lo, hi);
  }
}

// ---------------- GEMM: C[M,1024] = A[M,K] * B[1024,K]^T (+epilogue) ------
// bf16 MFMA 16x16x32, 128x128 tile, BK=64, XOR-swizzled LDS, global_load_lds.
// EPI==0: C = acc + bias[n]  (bf16 out)
// EPI==1: C = acc + P[join[2m+1]][n]  (bf16 out)
template <int EPI, int K>
__global__ __launch_bounds__(256) void gemm_bt(
    const u16* __restrict__ A, const u16* __restrict__ Bw,
    u16* __restrict__ C, const float* __restrict__ bias,
    const int* __restrict__ join, const u16* __restrict__ P) {
  __shared__ u16 As[128 * 64];
  __shared__ u16 Bs[128 * 64];
  const int tid = threadIdx.x;
  const int lane = tid & 63;
  const int wave = tid >> 6;
  const int quad = lane >> 4;
  const int l16 = lane & 15;
  const int m0 = blockIdx.x * 128;
  const int n0 = blockIdx.y * 128;
  const int wm = (wave & 1) * 64;
  const int wn = (wave >> 1) * 64;

  f32x4 acc[4][4];
#pragma unroll
  for (int i = 0; i < 4; i++)
#pragma unroll
    for (int j = 0; j < 4; j++) acc[i][j] = (f32x4){0.f, 0.f, 0.f, 0.f};

  int srow[4], skoff[4], ldsoff[4];
#pragma unroll
  for (int jj = 0; jj < 4; jj++) {
    int c = jj * 256 + tid;
    srow[jj] = c >> 3;
    skoff[jj] = (((c & 7) ^ ((c >> 3) & 7)) * 8);
    ldsoff[jj] = (jj * 256 + (tid & ~63)) * 8;
  }
  const u16* Abase = A + (size_t)m0 * K;
  const u16* Bbase = Bw + (size_t)n0 * K;

  for (int k0 = 0; k0 < K; k0 += 64) {
#pragma unroll
    for (int jj = 0; jj < 4; jj++)
      async_copy16(Abase + (size_t)srow[jj] * K + k0 + skoff[jj], As + ldsoff[jj]);
#pragma unroll
    for (int jj = 0; jj < 4; jj++)
      async_copy16(Bbase + (size_t)srow[jj] * K + k0 + skoff[jj], Bs + ldsoff[jj]);
    __syncthreads();
#pragma unroll
    for (int ks = 0; ks < 2; ks++) {
      bf16x8 af[4], bfr[4];
#pragma unroll
      for (int i = 0; i < 4; i++) {
        int m = wm + i * 16 + l16;
        int jp = (ks * 4 + quad) ^ (m & 7);
        af[i] = *(const bf16x8*)&As[m * 64 + jp * 8];
      }
#pragma unroll
      for (int j = 0; j < 4; j++) {
        int n = wn + j * 16 + l16;
        int jp = (ks * 4 + quad) ^ (n & 7);
        bfr[j] = *(const bf16x8*)&Bs[n * 64 + jp * 8];
      }
#pragma unroll
      for (int i = 0; i < 4; i++)
#pragma unroll
        for (int j = 0; j < 4; j++)
          acc[i][j] = __builtin_amdgcn_mfma_f32_16x16x32_bf16(af[i], bfr[j], acc[i][j], 0, 0, 0);
    }
    __syncthreads();
  }

#pragma unroll
  for (int i = 0; i < 4; i++) {
    int mbase = m0 + wm + i * 16 + quad * 4;
#pragma unroll
    for (int j = 0; j < 4; j++) {
      int n = n0 + wn + j * 16 + l16;
      float badd = (EPI == 0) ? bias[n] : 0.f;
#pragma unroll
      for (int r = 0; r < 4; r++) {
        int m = mbase + r;
        float v = acc[i][j][r] + badd;
        if (EPI == 1) {
          int j1 = join[2 * m + 1];
          v += bf2f(P[(size_t)j1 * 1024 + n]);
        }
        C[(size_t)m * 1024 + n] = f2bf(v);
      }
    }
  }
}

// ---------------- K3: LSTM step 1, wave-per-fragment ----------------------
// h0=c0=0 -> f-gate dead. Lane l owns h = 4l..4l+3.
__global__ __launch_bounds__(256) void lstm_step1(
    const u16* __restrict__ P, const int* __restrict__ join,
    u16* __restrict__ h1, u16* __restrict__ c1) {
  int wave = threadIdx.x >> 6, lane = threadIdx.x & 63;
  int m = blockIdx.x * 4 + wave;
  if (m >= N_FRAG) return;
  int j0 = join[2 * m];
  const u16* row = P + (size_t)j0 * 1024 + lane * 4;
  ushort4 iv = *(const ushort4*)(row);
  ushort4 gv = *(const ushort4*)(row + 512);
  ushort4 ov = *(const ushort4*)(row + 768);
  const u16* ivp = (const u16*)&iv;
  const u16* gvp = (const u16*)&gv;
  const u16* ovp = (const u16*)&ov;
  ushort4 h4, c4;
  u16* h4p = (u16*)&h4;
  u16* c4p = (u16*)&c4;
#pragma unroll
  for (int k = 0; k < 4; k++) {
    float c = sigmoidf(bf2f(ivp[k])) * fast_tanh(bf2f(gvp[k]));
    float hv = sigmoidf(bf2f(ovp[k])) * fast_tanh(c);
    h4p[k] = f2bf(hv);
    c4p[k] = f2bf(c);
  }
  *(ushort4*)(h1 + (size_t)m * 256 + lane * 4) = h4;
  *(ushort4*)(c1 + (size_t)m * 256 + lane * 4) = c4;
}

// ------- K5: LSTM step 2 + attention over {h1,h2} + output head -----------
// wave-per-fragment; lane l owns h = 4l..4l+3. No LDS, no __syncthreads.
__global__ __launch_bounds__(256) void lstm_step2_attn_out(
    const u16* __restrict__ G2, const u16* __restrict__ c1,
    const u16* __restrict__ h1b, const float* __restrict__ Wg,
    const float* __restrict__ Wout, const float* __restrict__ bout,
    float* __restrict__ frag_out) {
  int wave = threadIdx.x >> 6, lane = threadIdx.x & 63;
  int m = blockIdx.x * 4 + wave;
  if (m >= N_FRAG) return;
  const u16* row = G2 + (size_t)m * 1024 + lane * 4;
  ushort4 iv = *(const ushort4*)(row);
  ushort4 fv = *(const ushort4*)(row + 256);
  ushort4 gv = *(const ushort4*)(row + 512);
  ushort4 ov = *(const ushort4*)(row + 768);
  ushort4 c4 = *(const ushort4*)(c1 + (size_t)m * 256 + lane * 4);
  ushort4 h4 = *(const ushort4*)(h1b + (size_t)m * 256 + lane * 4);
  float4 wg = *(const float4*)(Wg + lane * 4);
  const u16* ivp = (const u16*)&iv;
  const u16* fvp = (const u16*)&fv;
  const u16* gvp = (const u16*)&gv;
  const u16* ovp = (const u16*)&ov;
  const u16* c4p = (const u16*)&c4;
  const u16* h4p = (const u16*)&h4;
  const float* wgp = (const float*)&wg;

  float h1v[4], h2v[4];
  float p1 = 0.f, p2 = 0.f;
#pragma unroll
  for (int k = 0; k < 4; k++) {
    float c2 = sigmoidf(bf2f(fvp[k])) * bf2f(c4p[k]) +
               sigmoidf(bf2f(ivp[k])) * fast_tanh(bf2f(gvp[k]));
    float h2 = sigmoidf(bf2f(ovp[k])) * fast_tanh(c2);
    h2v[k] = h2;
    h1v[k] = bf2f(h4p[k]);
    p1 += h1v[k] * wgp[k];
    p2 += h2 * wgp[k];
  }
#pragma unroll
  for (int off = 32; off; off >>= 1) {
    p1 += __shfl_xor(p1, off);
    p2 += __shfl_xor(p2, off);
  }
  float mx = fmaxf(p1, p2);
  float e1 = __expf(p1 - mx), e2 = __expf(p2 - mx);
  float inv = __frcp_rn(e1 + e2);
  float a1 = e1 * inv, a2 = e2 * inv;

  // output head: acc[t] = sum_h frag[h] * Wout[h][t]
  float acc[8];
#pragma unroll
  for (int t = 0; t < 8; t++) acc[t] = 0.f;
#pragma unroll
  for (int k = 0; k < 4; k++) {
    float frag = a1 * h1v[k] + a2 * h2v[k];
    int h = lane * 4 + k;
    float4 w0 = *(const float4*)(Wout + h * 8);
    float4 w1 = *(const float4*)(Wout + h * 8 + 4);
    acc[0] += frag * w0.x; acc[1] += frag * w0.y;
    acc[2] += frag * w0.z; acc[3] += frag * w0.w;
    acc[4] += frag * w1.x; acc[5] += frag * w1.y;
    acc[6] += frag * w1.z; acc[7] += frag * w1.w;
  }
#pragma unroll
  for (int off = 32; off; off >>= 1)
#pragma unroll
    for (int t = 0; t < 8; t++) acc[t] += __shfl_xor(acc[t], off);
  if (lane == 0) {
    float4 o0, o1;
    o0.x = fmaxf(acc[0] + bout[0], 0.f);
    o0.y = fmaxf(acc[1] + bout[1], 0.f);
    o0.z = fmaxf(acc[2] + bout[2], 0.f);
    o0.w = fmaxf(acc[3] + bout[3], 0.f);
    o1.x = fmaxf(acc[4] + bout[4], 0.f);
    o1.y = fmaxf(acc[5] + bout[5], 0.f);
    o1.z = fmaxf(acc[6] + bout[6], 0.f);
    o1.w = fmaxf(acc[7] + bout[7], 0.f);
    *(float4*)(frag_out + (size_t)m * 8) = o0;
    *(float4*)(frag_out + (size_t)m * 8 + 4) = o1;
  }
}

// ---------------- K6: combine scatter-sum ---------------------------------
__global__ __launch_bounds__(256) void scatter_sum(
    const float* __restrict__ frag_out, const int* __restrict__ comb,
    float* __restrict__ out) {
  int tid = blockIdx.x * 256 + threadIdx.x;
  if (tid >= N_OUT * 8) return;
  int n = tid >> 3, t = tid & 7;
  float s = 0.f;
#pragma unroll
  for (int d = 0; d < 4; d++) {
    int f = comb[n * 4 + d];
    s += frag_out[(size_t)f * 8 + t];
  }
  out[tid] = s;
}

extern "C" void kernel_launch(void* const* d_in, const int* in_sizes, int n_in,
                              void* d_out, int out_size, void* d_ws, size_t ws_size,
                              hipStream_t stream) {
  const float* feature = (const float*)d_in[0];
  const float* WgL = (const float*)d_in[1];
  const float* WgR = (const float*)d_in[2];
  const float* Wih = (const float*)d_in[3];
  const float* Whh = (const float*)d_in[4];
  const float* bih = (const float*)d_in[5];
  const float* bhh = (const float*)d_in[6];
  const float* Wgf = (const float*)d_in[7];
  const float* Wout = (const float*)d_in[8];
  const float* bout = (const float*)d_in[9];
  const int* lostS = (const int*)d_in[10];
  const int* retS = (const int*)d_in[11];
  const int* joinS = (const int*)d_in[12];
  const int* combS = (const int*)d_in[13];
  float* out = (float*)d_out;

  char* ws = (char*)d_ws;
  size_t off = 0;
  auto alloc = [&](size_t bytes) -> char* {
    char* p = ws + off;
    off = (off + bytes + 255) & ~(size_t)255;
    return p;
  };
  u16* Wihb = (u16*)alloc((size_t)1024 * 512 * 2);
  u16* Whhb = (u16*)alloc((size_t)1024 * 256 * 2);
  float* bias = (float*)alloc(1024 * 4);
  u16* P = (u16*)alloc((size_t)M_CLEAV_PAD * 1024 * 2);
  u16* h1 = (u16*)alloc((size_t)N_FRAG * 256 * 2);
  u16* c1 = (u16*)alloc((size_t)N_FRAG * 256 * 2);
  float* frag_out = (float*)alloc((size_t)N_FRAG * 8 * 4);
  char* uni = alloc((size_t)N_FRAG * 1024 * 2);
  u16* cleav = (u16*)uni;
  u16* gates2 = (u16*)uni;

  prep_kernel<<<2048, 256, 0, stream>>>(Wih, Whh, bih, bhh, Wihb, Whhb, bias);
  attn_pull<<<N_CLEAV / 4, 256, 0, stream>>>(feature, WgL, WgR, lostS, retS, cleav);
  gemm_bt<0, 512><<<dim3(M_CLEAV_PAD / 128, 8), 256, 0, stream>>>(
      cleav, Wihb, P, bias, nullptr, nullptr);
  lstm_step1<<<N_FRAG / 4, 256, 0, stream>>>(P, joinS, h1, c1);
  gemm_bt<1, 256><<<dim3(N_FRAG / 128, 8), 256, 0, stream>>>(
      h1, Whhb, gates2, nullptr, joinS, P);
  lstm_step2_attn_out<<<N_FRAG / 4, 256, 0, stream>>>(
      gates2, c1, h1, Wgf, Wout, bout, frag_out);
  scatter_sum<<<(N_OUT * 8 + 255) / 256, 256, 0, stream>>>(frag_out, combS, out);
}

// Round 3
// 753.018 us; speedup vs baseline: 1.5276x; 1.1515x over previous
//
#include <hip/hip_runtime.h>

typedef unsigned short u16;
typedef unsigned int u32;
typedef float f32x4 __attribute__((ext_vector_type(4)));
typedef __bf16 bf16x8 __attribute__((ext_vector_type(8)));

#define F 256
#define T_OUT 8
#define N_MONO 150000
#define N_CLEAV 100000
#define N_FRAG 80000
#define N_OUT 40000
#define M_CLEAV_PAD 100096   // 782 * 128

static __device__ __forceinline__ u16 f2bf(float f) {
  u32 u = __float_as_uint(f);
  u32 r = (u + 0x7FFFu + ((u >> 16) & 1u)) >> 16;
  return (u16)r;
}
static __device__ __forceinline__ float bf2f(u16 b) {
  return __uint_as_float(((u32)b) << 16);
}
static __device__ __forceinline__ float sigmoidf(float x) {
  return __frcp_rn(1.0f + __expf(-x));
}
static __device__ __forceinline__ float fast_tanh(float x) {
  return 1.0f - 2.0f * __frcp_rn(__expf(2.0f * x) + 1.0f);
}
static __device__ __forceinline__ void async_copy16(const u16* g, const u16* l) {
  __builtin_amdgcn_global_load_lds(
      (const __attribute__((address_space(1))) u32*)g,
      (__attribute__((address_space(3))) u32*)l,
      16, 0, 0);
}

// ---------------- K0: weight cast + bias sum ----------------
__global__ __launch_bounds__(256) void prep_kernel(
    const float* __restrict__ Wih, const float* __restrict__ Whh,
    const float* __restrict__ bih, const float* __restrict__ bhh,
    u16* __restrict__ Wihb, u16* __restrict__ Whhb, float* __restrict__ bias) {
  int i = blockIdx.x * 256 + threadIdx.x;
  if (i < 1024 * 512) Wihb[i] = f2bf(Wih[i]);
  if (i < 1024 * 256) Whhb[i] = f2bf(Whh[i]);
  if (i < 1024) bias[i] = bih[i] + bhh[i];
}

// ---------------- K1: attention pulls -> cleav [N_CLEAV, 512] bf16 --------
// one wave per cleavage node; lane holds feature slots [4*lane .. 4*lane+3]
__global__ __launch_bounds__(256) void attn_pull(
    const float* __restrict__ feat, const float* __restrict__ WgL,
    const float* __restrict__ WgR, const int* __restrict__ lostS,
    const int* __restrict__ retS, u16* __restrict__ cleav) {
  int wave = threadIdx.x >> 6, lane = threadIdx.x & 63;
  int n = blockIdx.x * 4 + wave;
  if (n >= N_CLEAV) return;
  const float4 wgl = *(const float4*)(WgL + lane * 4);
  const float4 wgr = *(const float4*)(WgR + lane * 4);
  for (int sg = 0; sg < 2; ++sg) {
    const int* src = sg ? retS : lostS;
    float4 wg = sg ? wgr : wgl;
    int4 ridx = *(const int4*)(src + n * 4);
    int r[4] = {ridx.x, ridx.y, ridx.z, ridx.w};
    float4 x[4];
#pragma unroll
    for (int d = 0; d < 4; ++d)
      x[d] = *(const float4*)(feat + (size_t)r[d] * F + lane * 4);
    float logit[4];
#pragma unroll
    for (int d = 0; d < 4; ++d) {
      float p = x[d].x * wg.x + x[d].y * wg.y + x[d].z * wg.z + x[d].w * wg.w;
#pragma unroll
      for (int off = 32; off; off >>= 1) p += __shfl_xor(p, off);
      logit[d] = p;
    }
    float mx = fmaxf(fmaxf(logit[0], logit[1]), fmaxf(logit[2], logit[3]));
    float e0 = __expf(logit[0] - mx), e1 = __expf(logit[1] - mx);
    float e2 = __expf(logit[2] - mx), e3 = __expf(logit[3] - mx);
    float inv = 1.f / (e0 + e1 + e2 + e3);
    float a0 = e0 * inv, a1 = e1 * inv, a2 = e2 * inv, a3 = e3 * inv;
    float4 acc;
    acc.x = a0 * x[0].x + a1 * x[1].x + a2 * x[2].x + a3 * x[3].x;
    acc.y = a0 * x[0].y + a1 * x[1].y + a2 * x[2].y + a3 * x[3].y;
    acc.z = a0 * x[0].z + a1 * x[1].z + a2 * x[2].z + a3 * x[3].z;
    acc.w = a0 * x[0].w + a1 * x[1].w + a2 * x[2].w + a3 * x[3].w;
    u32 lo = (u32)f2bf(acc.x) | ((u32)f2bf(acc.y) << 16);
    u32 hi = (u32)f2bf(acc.z) | ((u32)f2bf(acc.w) << 16);
    *(uint2*)(cleav + (size_t)n * 512 + sg * 256 + lane * 4) = make_uint2(lo, hi);
  }
}

// ---------------- GEMM: C[M,1024] = A[M,K] * B[1024,K]^T ------------------
// bf16 MFMA 16x16x32, 128x128 tile, BK=32, DOUBLE-buffered LDS (32 KB),
// XOR-swizzled chunks, global_load_lds width 16. grid.x = N-strip (8) so
// consecutive blocks share the A M-strip (fetch A from HBM ~once).
// EPI==0: C = acc + bias[n]; EPI==1: C = acc.
template <int EPI, int K>
__global__ __launch_bounds__(256, 4) void gemm_bt(
    const u16* __restrict__ A, const u16* __restrict__ Bw,
    u16* __restrict__ C, const float* __restrict__ bias) {
  __shared__ u16 As[2][128 * 32];
  __shared__ u16 Bs[2][128 * 32];
  const int tid = threadIdx.x;
  const int lane = tid & 63;
  const int wave = tid >> 6;
  const int quad = lane >> 4;
  const int l16 = lane & 15;
  const int n0 = blockIdx.x * 128;
  const int m0 = blockIdx.y * 128;
  const int wm = (wave & 1) * 64;
  const int wn = (wave >> 1) * 64;

  f32x4 acc[4][4];
#pragma unroll
  for (int i = 0; i < 4; i++)
#pragma unroll
    for (int j = 0; j < 4; j++) acc[i][j] = (f32x4){0.f, 0.f, 0.f, 0.f};

  // staging: chunk c = jj*256+tid in [0,512); row = c>>2 (4x16B per 64B row);
  // phys chunk = c&3; logical k-chunk = (c&3)^(row&3)  (XOR swizzle)
  int srow[2], skoff[2], ldsoff[2];
#pragma unroll
  for (int jj = 0; jj < 2; jj++) {
    int c = jj * 256 + tid;
    srow[jj] = c >> 2;
    skoff[jj] = ((c & 3) ^ ((c >> 2) & 3)) * 8;
    ldsoff[jj] = (jj * 256 + (tid & ~63)) * 8;  // u16 units; HW adds lane*16B
  }
  const u16* Abase = A + (size_t)m0 * K;
  const u16* Bbase = Bw + (size_t)n0 * K;

  auto stage = [&](int buf, int k0) {
#pragma unroll
    for (int jj = 0; jj < 2; jj++)
      async_copy16(Abase + (size_t)srow[jj] * K + k0 + skoff[jj], &As[buf][ldsoff[jj]]);
#pragma unroll
    for (int jj = 0; jj < 2; jj++)
      async_copy16(Bbase + (size_t)srow[jj] * K + k0 + skoff[jj], &Bs[buf][ldsoff[jj]]);
  };

  stage(0, 0);
  const int nK = K / 32;
  for (int t = 0; t < nK; ++t) {
    __syncthreads();                 // drains stage t (vmcnt) + iter t-1 ds_reads
    if (t + 1 < nK) stage((t + 1) & 1, (t + 1) * 32);
    const int buf = t & 1;
    bf16x8 af[4], bfr[4];
#pragma unroll
    for (int i = 0; i < 4; i++) {
      int m = wm + i * 16 + l16;
      int jp = quad ^ (m & 3);
      af[i] = *(const bf16x8*)&As[buf][m * 32 + jp * 8];
    }
#pragma unroll
    for (int j = 0; j < 4; j++) {
      int n = wn + j * 16 + l16;
      int jp = quad ^ (n & 3);
      bfr[j] = *(const bf16x8*)&Bs[buf][n * 32 + jp * 8];
    }
#pragma unroll
    for (int i = 0; i < 4; i++)
#pragma unroll
      for (int j = 0; j < 4; j++)
        acc[i][j] = __builtin_amdgcn_mfma_f32_16x16x32_bf16(af[i], bfr[j], acc[i][j], 0, 0, 0);
  }

  // epilogue: C/D layout col=lane&15, row=quad*4+reg
#pragma unroll
  for (int i = 0; i < 4; i++) {
    int mbase = m0 + wm + i * 16 + quad * 4;
#pragma unroll
    for (int j = 0; j < 4; j++) {
      int n = n0 + wn + j * 16 + l16;
      float badd = (EPI == 0) ? bias[n] : 0.f;
#pragma unroll
      for (int r = 0; r < 4; r++) {
        int m = mbase + r;
        C[(size_t)m * 1024 + n] = f2bf(acc[i][j][r] + badd);
      }
    }
  }
}

// ---------------- K3: LSTM step 1, wave-per-fragment ----------------------
// h0=c0=0 -> f-gate dead. Lane l owns h = 4l..4l+3.
__global__ __launch_bounds__(256) void lstm_step1(
    const u16* __restrict__ P, const int* __restrict__ join,
    u16* __restrict__ h1, u16* __restrict__ c1) {
  int wave = threadIdx.x >> 6, lane = threadIdx.x & 63;
  int m = blockIdx.x * 4 + wave;
  if (m >= N_FRAG) return;
  int j0 = join[2 * m];
  const u16* row = P + (size_t)j0 * 1024 + lane * 4;
  ushort4 iv = *(const ushort4*)(row);
  ushort4 gv = *(const ushort4*)(row + 512);
  ushort4 ov = *(const ushort4*)(row + 768);
  const u16* ivp = (const u16*)&iv;
  const u16* gvp = (const u16*)&gv;
  const u16* ovp = (const u16*)&ov;
  ushort4 h4, c4;
  u16* h4p = (u16*)&h4;
  u16* c4p = (u16*)&c4;
#pragma unroll
  for (int k = 0; k < 4; k++) {
    float c = sigmoidf(bf2f(ivp[k])) * fast_tanh(bf2f(gvp[k]));
    float hv = sigmoidf(bf2f(ovp[k])) * fast_tanh(c);
    h4p[k] = f2bf(hv);
    c4p[k] = f2bf(c);
  }
  *(ushort4*)(h1 + (size_t)m * 256 + lane * 4) = h4;
  *(ushort4*)(c1 + (size_t)m * 256 + lane * 4) = c4;
}

// ------- K5: LSTM step 2 + attention over {h1,h2} + output head -----------
// wave-per-fragment. gates2 = G2(matmul) + P[join[2m+1]] (row-coalesced).
__global__ __launch_bounds__(256) void lstm_step2_attn_out(
    const u16* __restrict__ G2, const u16* __restrict__ P,
    const int* __restrict__ join, const u16* __restrict__ c1,
    const u16* __restrict__ h1b, const float* __restrict__ Wg,
    const float* __restrict__ Wout, const float* __restrict__ bout,
    float* __restrict__ frag_out) {
  int wave = threadIdx.x >> 6, lane = threadIdx.x & 63;
  int m = blockIdx.x * 4 + wave;
  if (m >= N_FRAG) return;
  int j1 = join[2 * m + 1];
  const u16* row = G2 + (size_t)m * 1024 + lane * 4;
  const u16* prow = P + (size_t)j1 * 1024 + lane * 4;
  ushort4 iv = *(const ushort4*)(row);
  ushort4 fv = *(const ushort4*)(row + 256);
  ushort4 gv = *(const ushort4*)(row + 512);
  ushort4 ov = *(const ushort4*)(row + 768);
  ushort4 pi = *(const ushort4*)(prow);
  ushort4 pf = *(const ushort4*)(prow + 256);
  ushort4 pg = *(const ushort4*)(prow + 512);
  ushort4 po = *(const ushort4*)(prow + 768);
  ushort4 c4 = *(const ushort4*)(c1 + (size_t)m * 256 + lane * 4);
  ushort4 h4 = *(const ushort4*)(h1b + (size_t)m * 256 + lane * 4);
  float4 wg = *(const float4*)(Wg + lane * 4);
  const u16* ivp = (const u16*)&iv; const u16* pip = (const u16*)&pi;
  const u16* fvp = (const u16*)&fv; const u16* pfp = (const u16*)&pf;
  const u16* gvp = (const u16*)&gv; const u16* pgp = (const u16*)&pg;
  const u16* ovp = (const u16*)&ov; const u16* pop = (const u16*)&po;
  const u16* c4p = (const u16*)&c4;
  const u16* h4p = (const u16*)&h4;
  const float* wgp = (const float*)&wg;

  float h1v[4], h2v[4];
  float p1 = 0.f, p2 = 0.f;
#pragma unroll
  for (int k = 0; k < 4; k++) {
    float gi = bf2f(ivp[k]) + bf2f(pip[k]);
    float gf = bf2f(fvp[k]) + bf2f(pfp[k]);
    float gg = bf2f(gvp[k]) + bf2f(pgp[k]);
    float go = bf2f(ovp[k]) + bf2f(pop[k]);
    float c2 = sigmoidf(gf) * bf2f(c4p[k]) + sigmoidf(gi) * fast_tanh(gg);
    float h2 = sigmoidf(go) * fast_tanh(c2);
    h2v[k] = h2;
    h1v[k] = bf2f(h4p[k]);
    p1 += h1v[k] * wgp[k];
    p2 += h2 * wgp[k];
  }
#pragma unroll
  for (int off = 32; off; off >>= 1) {
    p1 += __shfl_xor(p1, off);
    p2 += __shfl_xor(p2, off);
  }
  float mx = fmaxf(p1, p2);
  float e1 = __expf(p1 - mx), e2 = __expf(p2 - mx);
  float inv = __frcp_rn(e1 + e2);
  float a1 = e1 * inv, a2 = e2 * inv;

  float acc[8];
#pragma unroll
  for (int t = 0; t < 8; t++) acc[t] = 0.f;
#pragma unroll
  for (int k = 0; k < 4; k++) {
    float frag = a1 * h1v[k] + a2 * h2v[k];
    int h = lane * 4 + k;
    float4 w0 = *(const float4*)(Wout + h * 8);
    float4 w1 = *(const float4*)(Wout + h * 8 + 4);
    acc[0] += frag * w0.x; acc[1] += frag * w0.y;
    acc[2] += frag * w0.z; acc[3] += frag * w0.w;
    acc[4] += frag * w1.x; acc[5] += frag * w1.y;
    acc[6] += frag * w1.z; acc[7] += frag * w1.w;
  }
#pragma unroll
  for (int off = 32; off; off >>= 1)
#pragma unroll
    for (int t = 0; t < 8; t++) acc[t] += __shfl_xor(acc[t], off);
  if (lane == 0) {
    float4 o0, o1;
    o0.x = fmaxf(acc[0] + bout[0], 0.f);
    o0.y = fmaxf(acc[1] + bout[1], 0.f);
    o0.z = fmaxf(acc[2] + bout[2], 0.f);
    o0.w = fmaxf(acc[3] + bout[3], 0.f);
    o1.x = fmaxf(acc[4] + bout[4], 0.f);
    o1.y = fmaxf(acc[5] + bout[5], 0.f);
    o1.z = fmaxf(acc[6] + bout[6], 0.f);
    o1.w = fmaxf(acc[7] + bout[7], 0.f);
    *(float4*)(frag_out + (size_t)m * 8) = o0;
    *(float4*)(frag_out + (size_t)m * 8 + 4) = o1;
  }
}

// ---------------- K6: combine scatter-sum ---------------------------------
__global__ __launch_bounds__(256) void scatter_sum(
    const float* __restrict__ frag_out, const int* __restrict__ comb,
    float* __restrict__ out) {
  int tid = blockIdx.x * 256 + threadIdx.x;
  if (tid >= N_OUT * 8) return;
  int n = tid >> 3, t = tid & 7;
  float s = 0.f;
#pragma unroll
  for (int d = 0; d < 4; d++) {
    int f = comb[n * 4 + d];
    s += frag_out[(size_t)f * 8 + t];
  }
  out[tid] = s;
}

extern "C" void kernel_launch(void* const* d_in, const int* in_sizes, int n_in,
                              void* d_out, int out_size, void* d_ws, size_t ws_size,
                              hipStream_t stream) {
  const float* feature = (const float*)d_in[0];
  const float* WgL = (const float*)d_in[1];
  const float* WgR = (const float*)d_in[2];
  const float* Wih = (const float*)d_in[3];
  const float* Whh = (const float*)d_in[4];
  const float* bih = (const float*)d_in[5];
  const float* bhh = (const float*)d_in[6];
  const float* Wgf = (const float*)d_in[7];
  const float* Wout = (const float*)d_in[8];
  const float* bout = (const float*)d_in[9];
  const int* lostS = (const int*)d_in[10];
  const int* retS = (const int*)d_in[11];
  const int* joinS = (const int*)d_in[12];
  const int* combS = (const int*)d_in[13];
  float* out = (float*)d_out;

  char* ws = (char*)d_ws;
  size_t off = 0;
  auto alloc = [&](size_t bytes) -> char* {
    char* p = ws + off;
    off = (off + bytes + 255) & ~(size_t)255;
    return p;
  };
  u16* Wihb = (u16*)alloc((size_t)1024 * 512 * 2);
  u16* Whhb = (u16*)alloc((size_t)1024 * 256 * 2);
  float* bias = (float*)alloc(1024 * 4);
  u16* P = (u16*)alloc((size_t)M_CLEAV_PAD * 1024 * 2);
  u16* h1 = (u16*)alloc((size_t)N_FRAG * 256 * 2);
  u16* c1 = (u16*)alloc((size_t)N_FRAG * 256 * 2);
  float* frag_out = (float*)alloc((size_t)N_FRAG * 8 * 4);
  char* uni = alloc((size_t)N_FRAG * 1024 * 2);
  u16* cleav = (u16*)uni;
  u16* gates2 = (u16*)uni;

  prep_kernel<<<2048, 256, 0, stream>>>(Wih, Whh, bih, bhh, Wihb, Whhb, bias);
  attn_pull<<<N_CLEAV / 4, 256, 0, stream>>>(feature, WgL, WgR, lostS, retS, cleav);
  gemm_bt<0, 512><<<dim3(8, M_CLEAV_PAD / 128), 256, 0, stream>>>(cleav, Wihb, P, bias);
  lstm_step1<<<N_FRAG / 4, 256, 0, stream>>>(P, joinS, h1, c1);
  gemm_bt<1, 256><<<dim3(8, N_FRAG / 128), 256, 0, stream>>>(h1, Whhb, gates2, nullptr);
  lstm_step2_attn_out<<<N_FRAG / 4, 256, 0, stream>>>(
      gates2, P, joinS, c1, h1, Wgf, Wout, bout, frag_out);
  scatter_sum<<<(N_OUT * 8 + 255) / 256, 256, 0, stream>>>(frag_out, combS, out);
}

// Round 4
// 746.617 us; speedup vs baseline: 1.5407x; 1.0086x over previous
//
#include <hip/hip_runtime.h>

typedef unsigned short u16;
typedef unsigned int u32;
typedef float f32x4 __attribute__((ext_vector_type(4)));
typedef __bf16 bf16x8 __attribute__((ext_vector_type(8)));

#define F 256
#define T_OUT 8
#define N_MONO 150000
#define N_CLEAV 100000
#define N_FRAG 80000
#define N_OUT 40000
#define M_CLEAV_PAD 100352   // 784 * 128 (98 strips per XCD * 8)

static __device__ __forceinline__ u16 f2bf(float f) {
  u32 u = __float_as_uint(f);
  u32 r = (u + 0x7FFFu + ((u >> 16) & 1u)) >> 16;
  return (u16)r;
}
static __device__ __forceinline__ float bf2f(u16 b) {
  return __uint_as_float(((u32)b) << 16);
}
static __device__ __forceinline__ float sigmoidf(float x) {
  return __frcp_rn(1.0f + __expf(-x));
}
static __device__ __forceinline__ float fast_tanh(float x) {
  return 1.0f - 2.0f * __frcp_rn(__expf(2.0f * x) + 1.0f);
}
static __device__ __forceinline__ void async_copy16(const u16* g, const u16* l) {
  __builtin_amdgcn_global_load_lds(
      (const __attribute__((address_space(1))) u32*)g,
      (__attribute__((address_space(3))) u32*)l,
      16, 0, 0);
}

// ---------------- K0: weight cast + bias sum ----------------
__global__ __launch_bounds__(256) void prep_kernel(
    const float* __restrict__ Wih, const float* __restrict__ Whh,
    const float* __restrict__ bih, const float* __restrict__ bhh,
    u16* __restrict__ Wihb, u16* __restrict__ Whhb, float* __restrict__ bias) {
  int i = blockIdx.x * 256 + threadIdx.x;
  if (i < 1024 * 512) Wihb[i] = f2bf(Wih[i]);
  if (i < 1024 * 256) Whhb[i] = f2bf(Whh[i]);
  if (i < 1024) bias[i] = bih[i] + bhh[i];
}

// ---------------- K1: attention pulls -> cleav [N_CLEAV, 512] bf16 --------
__global__ __launch_bounds__(256) void attn_pull(
    const float* __restrict__ feat, const float* __restrict__ WgL,
    const float* __restrict__ WgR, const int* __restrict__ lostS,
    const int* __restrict__ retS, u16* __restrict__ cleav) {
  int wave = threadIdx.x >> 6, lane = threadIdx.x & 63;
  int n = blockIdx.x * 4 + wave;
  if (n >= N_CLEAV) return;
  const float4 wgl = *(const float4*)(WgL + lane * 4);
  const float4 wgr = *(const float4*)(WgR + lane * 4);
  for (int sg = 0; sg < 2; ++sg) {
    const int* src = sg ? retS : lostS;
    float4 wg = sg ? wgr : wgl;
    int4 ridx = *(const int4*)(src + n * 4);
    int r[4] = {ridx.x, ridx.y, ridx.z, ridx.w};
    float4 x[4];
#pragma unroll
    for (int d = 0; d < 4; ++d)
      x[d] = *(const float4*)(feat + (size_t)r[d] * F + lane * 4);
    float logit[4];
#pragma unroll
    for (int d = 0; d < 4; ++d) {
      float p = x[d].x * wg.x + x[d].y * wg.y + x[d].z * wg.z + x[d].w * wg.w;
#pragma unroll
      for (int off = 32; off; off >>= 1) p += __shfl_xor(p, off);
      logit[d] = p;
    }
    float mx = fmaxf(fmaxf(logit[0], logit[1]), fmaxf(logit[2], logit[3]));
    float e0 = __expf(logit[0] - mx), e1 = __expf(logit[1] - mx);
    float e2 = __expf(logit[2] - mx), e3 = __expf(logit[3] - mx);
    float inv = 1.f / (e0 + e1 + e2 + e3);
    float a0 = e0 * inv, a1 = e1 * inv, a2 = e2 * inv, a3 = e3 * inv;
    float4 acc;
    acc.x = a0 * x[0].x + a1 * x[1].x + a2 * x[2].x + a3 * x[3].x;
    acc.y = a0 * x[0].y + a1 * x[1].y + a2 * x[2].y + a3 * x[3].y;
    acc.z = a0 * x[0].z + a1 * x[1].z + a2 * x[2].z + a3 * x[3].z;
    acc.w = a0 * x[0].w + a1 * x[1].w + a2 * x[2].w + a3 * x[3].w;
    u32 lo = (u32)f2bf(acc.x) | ((u32)f2bf(acc.y) << 16);
    u32 hi = (u32)f2bf(acc.z) | ((u32)f2bf(acc.w) << 16);
    *(uint2*)(cleav + (size_t)n * 512 + sg * 256 + lane * 4) = make_uint2(lo, hi);
  }
}

// ---------------- GEMM: C[M,1024] = A[M,K] * B[1024,K]^T ------------------
// bf16 MFMA 16x16x32, 128x128 tile, BK=32, double-buffered LDS (32 KB),
// XOR-swizzled on (m>>1)&3 (conflict-free: quarter-wave covers all 8 16B
// bank-groups 2x), global_load_lds width 16.
// XCD-aware remap: xcd = blockIdx&7 owns strips [xcd*nper, xcd*nper+nper);
// within an xcd the 8 N-strips of one M-strip are adjacent -> A hits L2.
// EPI==0: C = acc + bias[n]; EPI==1: C = acc.
template <int EPI, int K>
__global__ __launch_bounds__(256, 4) void gemm_bt(
    const u16* __restrict__ A, const u16* __restrict__ Bw,
    u16* __restrict__ C, const float* __restrict__ bias,
    int nper, int mstrips_valid) {
  __shared__ u16 As[2][128 * 32];
  __shared__ u16 Bs[2][128 * 32];
  const int flat = blockIdx.x;
  const int xcd = flat & 7;
  const int w = flat >> 3;
  const int mstrip = xcd * nper + (w >> 3);
  const int nstrip = w & 7;
  if (mstrip >= mstrips_valid) return;
  const int m0 = mstrip * 128;
  const int n0 = nstrip * 128;

  const int tid = threadIdx.x;
  const int lane = tid & 63;
  const int wave = tid >> 6;
  const int quad = lane >> 4;
  const int l16 = lane & 15;
  const int wm = (wave & 1) * 64;
  const int wn = (wave >> 1) * 64;

  f32x4 acc[4][4];
#pragma unroll
  for (int i = 0; i < 4; i++)
#pragma unroll
    for (int j = 0; j < 4; j++) acc[i][j] = (f32x4){0.f, 0.f, 0.f, 0.f};

  // staging: chunk c = jj*256+tid in [0,512); row = c>>2; phys chunk = c&3;
  // logical k-chunk = (c&3) ^ ((row>>1)&3) = (c&3) ^ ((c>>3)&3)
  int srow[2], skoff[2], ldsoff[2];
#pragma unroll
  for (int jj = 0; jj < 2; jj++) {
    int c = jj * 256 + tid;
    srow[jj] = c >> 2;
    skoff[jj] = ((c & 3) ^ ((c >> 3) & 3)) * 8;
    ldsoff[jj] = (jj * 256 + (tid & ~63)) * 8;  // u16 units; HW adds lane*16B
  }
  const u16* Abase = A + (size_t)m0 * K;
  const u16* Bbase = Bw + (size_t)n0 * K;

  auto stage = [&](int buf, int k0) {
#pragma unroll
    for (int jj = 0; jj < 2; jj++)
      async_copy16(Abase + (size_t)srow[jj] * K + k0 + skoff[jj], &As[buf][ldsoff[jj]]);
#pragma unroll
    for (int jj = 0; jj < 2; jj++)
      async_copy16(Bbase + (size_t)srow[jj] * K + k0 + skoff[jj], &Bs[buf][ldsoff[jj]]);
  };

  stage(0, 0);
  const int nK = K / 32;
  for (int t = 0; t < nK; ++t) {
    __syncthreads();                 // drains stage t (vmcnt) + iter t-1 ds_reads
    if (t + 1 < nK) stage((t + 1) & 1, (t + 1) * 32);
    const int buf = t & 1;
    bf16x8 af[4], bfr[4];
#pragma unroll
    for (int i = 0; i < 4; i++) {
      int m = wm + i * 16 + l16;
      int jp = quad ^ ((m >> 1) & 3);
      af[i] = *(const bf16x8*)&As[buf][m * 32 + jp * 8];
    }
#pragma unroll
    for (int j = 0; j < 4; j++) {
      int n = wn + j * 16 + l16;
      int jp = quad ^ ((n >> 1) & 3);
      bfr[j] = *(const bf16x8*)&Bs[buf][n * 32 + jp * 8];
    }
#pragma unroll
    for (int i = 0; i < 4; i++)
#pragma unroll
      for (int j = 0; j < 4; j++)
        acc[i][j] = __builtin_amdgcn_mfma_f32_16x16x32_bf16(af[i], bfr[j], acc[i][j], 0, 0, 0);
  }

  // epilogue: C/D layout col=lane&15, row=quad*4+reg
#pragma unroll
  for (int i = 0; i < 4; i++) {
    int mbase = m0 + wm + i * 16 + quad * 4;
#pragma unroll
    for (int j = 0; j < 4; j++) {
      int n = n0 + wn + j * 16 + l16;
      float badd = (EPI == 0) ? bias[n] : 0.f;
#pragma unroll
      for (int r = 0; r < 4; r++) {
        int m = mbase + r;
        C[(size_t)m * 1024 + n] = f2bf(acc[i][j][r] + badd);
      }
    }
  }
}

// ---------------- K3: LSTM step 1, wave-per-fragment ----------------------
__global__ __launch_bounds__(256) void lstm_step1(
    const u16* __restrict__ P, const int* __restrict__ join,
    u16* __restrict__ h1, u16* __restrict__ c1) {
  int wave = threadIdx.x >> 6, lane = threadIdx.x & 63;
  int m = blockIdx.x * 4 + wave;
  if (m >= N_FRAG) return;
  int j0 = join[2 * m];
  const u16* row = P + (size_t)j0 * 1024 + lane * 4;
  ushort4 iv = *(const ushort4*)(row);
  ushort4 gv = *(const ushort4*)(row + 512);
  ushort4 ov = *(const ushort4*)(row + 768);
  const u16* ivp = (const u16*)&iv;
  const u16* gvp = (const u16*)&gv;
  const u16* ovp = (const u16*)&ov;
  ushort4 h4, c4;
  u16* h4p = (u16*)&h4;
  u16* c4p = (u16*)&c4;
#pragma unroll
  for (int k = 0; k < 4; k++) {
    float c = sigmoidf(bf2f(ivp[k])) * fast_tanh(bf2f(gvp[k]));
    float hv = sigmoidf(bf2f(ovp[k])) * fast_tanh(c);
    h4p[k] = f2bf(hv);
    c4p[k] = f2bf(c);
  }
  *(ushort4*)(h1 + (size_t)m * 256 + lane * 4) = h4;
  *(ushort4*)(c1 + (size_t)m * 256 + lane * 4) = c4;
}

// ------- K5: LSTM step 2 + attention over {h1,h2} + output head -----------
__global__ __launch_bounds__(256) void lstm_step2_attn_out(
    const u16* __restrict__ G2, const u16* __restrict__ P,
    const int* __restrict__ join, const u16* __restrict__ c1,
    const u16* __restrict__ h1b, const float* __restrict__ Wg,
    const float* __restrict__ Wout, const float* __restrict__ bout,
    float* __restrict__ frag_out) {
  int wave = threadIdx.x >> 6, lane = threadIdx.x & 63;
  int m = blockIdx.x * 4 + wave;
  if (m >= N_FRAG) return;
  int j1 = join[2 * m + 1];
  const u16* row = G2 + (size_t)m * 1024 + lane * 4;
  const u16* prow = P + (size_t)j1 * 1024 + lane * 4;
  ushort4 iv = *(const ushort4*)(row);
  ushort4 fv = *(const ushort4*)(row + 256);
  ushort4 gv = *(const ushort4*)(row + 512);
  ushort4 ov = *(const ushort4*)(row + 768);
  ushort4 pi = *(const ushort4*)(prow);
  ushort4 pf = *(const ushort4*)(prow + 256);
  ushort4 pg = *(const ushort4*)(prow + 512);
  ushort4 po = *(const ushort4*)(prow + 768);
  ushort4 c4 = *(const ushort4*)(c1 + (size_t)m * 256 + lane * 4);
  ushort4 h4 = *(const ushort4*)(h1b + (size_t)m * 256 + lane * 4);
  float4 wg = *(const float4*)(Wg + lane * 4);
  const u16* ivp = (const u16*)&iv; const u16* pip = (const u16*)&pi;
  const u16* fvp = (const u16*)&fv; const u16* pfp = (const u16*)&pf;
  const u16* gvp = (const u16*)&gv; const u16* pgp = (const u16*)&pg;
  const u16* ovp = (const u16*)&ov; const u16* pop = (const u16*)&po;
  const u16* c4p = (const u16*)&c4;
  const u16* h4p = (const u16*)&h4;
  const float* wgp = (const float*)&wg;

  float h1v[4], h2v[4];
  float p1 = 0.f, p2 = 0.f;
#pragma unroll
  for (int k = 0; k < 4; k++) {
    float gi = bf2f(ivp[k]) + bf2f(pip[k]);
    float gf = bf2f(fvp[k]) + bf2f(pfp[k]);
    float gg = bf2f(gvp[k]) + bf2f(pgp[k]);
    float go = bf2f(ovp[k]) + bf2f(pop[k]);
    float c2 = sigmoidf(gf) * bf2f(c4p[k]) + sigmoidf(gi) * fast_tanh(gg);
    float h2 = sigmoidf(go) * fast_tanh(c2);
    h2v[k] = h2;
    h1v[k] = bf2f(h4p[k]);
    p1 += h1v[k] * wgp[k];
    p2 += h2 * wgp[k];
  }
#pragma unroll
  for (int off = 32; off; off >>= 1) {
    p1 += __shfl_xor(p1, off);
    p2 += __shfl_xor(p2, off);
  }
  float mx = fmaxf(p1, p2);
  float e1 = __expf(p1 - mx), e2 = __expf(p2 - mx);
  float inv = __frcp_rn(e1 + e2);
  float a1 = e1 * inv, a2 = e2 * inv;

  float acc[8];
#pragma unroll
  for (int t = 0; t < 8; t++) acc[t] = 0.f;
#pragma unroll
  for (int k = 0; k < 4; k++) {
    float frag = a1 * h1v[k] + a2 * h2v[k];
    int h = lane * 4 + k;
    float4 w0 = *(const float4*)(Wout + h * 8);
    float4 w1 = *(const float4*)(Wout + h * 8 + 4);
    acc[0] += frag * w0.x; acc[1] += frag * w0.y;
    acc[2] += frag * w0.z; acc[3] += frag * w0.w;
    acc[4] += frag * w1.x; acc[5] += frag * w1.y;
    acc[6] += frag * w1.z; acc[7] += frag * w1.w;
  }
#pragma unroll
  for (int off = 32; off; off >>= 1)
#pragma unroll
    for (int t = 0; t < 8; t++) acc[t] += __shfl_xor(acc[t], off);
  if (lane == 0) {
    float4 o0, o1;
    o0.x = fmaxf(acc[0] + bout[0], 0.f);
    o0.y = fmaxf(acc[1] + bout[1], 0.f);
    o0.z = fmaxf(acc[2] + bout[2], 0.f);
    o0.w = fmaxf(acc[3] + bout[3], 0.f);
    o1.x = fmaxf(acc[4] + bout[4], 0.f);
    o1.y = fmaxf(acc[5] + bout[5], 0.f);
    o1.z = fmaxf(acc[6] + bout[6], 0.f);
    o1.w = fmaxf(acc[7] + bout[7], 0.f);
    *(float4*)(frag_out + (size_t)m * 8) = o0;
    *(float4*)(frag_out + (size_t)m * 8 + 4) = o1;
  }
}

// ---------------- K6: combine scatter-sum ---------------------------------
__global__ __launch_bounds__(256) void scatter_sum(
    const float* __restrict__ frag_out, const int* __restrict__ comb,
    float* __restrict__ out) {
  int tid = blockIdx.x * 256 + threadIdx.x;
  if (tid >= N_OUT * 8) return;
  int n = tid >> 3, t = tid & 7;
  float s = 0.f;
#pragma unroll
  for (int d = 0; d < 4; d++) {
    int f = comb[n * 4 + d];
    s += frag_out[(size_t)f * 8 + t];
  }
  out[tid] = s;
}

extern "C" void kernel_launch(void* const* d_in, const int* in_sizes, int n_in,
                              void* d_out, int out_size, void* d_ws, size_t ws_size,
                              hipStream_t stream) {
  const float* feature = (const float*)d_in[0];
  const float* WgL = (const float*)d_in[1];
  const float* WgR = (const float*)d_in[2];
  const float* Wih = (const float*)d_in[3];
  const float* Whh = (const float*)d_in[4];
  const float* bih = (const float*)d_in[5];
  const float* bhh = (const float*)d_in[6];
  const float* Wgf = (const float*)d_in[7];
  const float* Wout = (const float*)d_in[8];
  const float* bout = (const float*)d_in[9];
  const int* lostS = (const int*)d_in[10];
  const int* retS = (const int*)d_in[11];
  const int* joinS = (const int*)d_in[12];
  const int* combS = (const int*)d_in[13];
  float* out = (float*)d_out;

  char* ws = (char*)d_ws;
  size_t off = 0;
  auto alloc = [&](size_t bytes) -> char* {
    char* p = ws + off;
    off = (off + bytes + 255) & ~(size_t)255;
    return p;
  };
  u16* Wihb = (u16*)alloc((size_t)1024 * 512 * 2);
  u16* Whhb = (u16*)alloc((size_t)1024 * 256 * 2);
  float* bias = (float*)alloc(1024 * 4);
  u16* P = (u16*)alloc((size_t)M_CLEAV_PAD * 1024 * 2);
  u16* h1 = (u16*)alloc((size_t)N_FRAG * 256 * 2);
  u16* c1 = (u16*)alloc((size_t)N_FRAG * 256 * 2);
  float* frag_out = (float*)alloc((size_t)N_FRAG * 8 * 4);
  char* uni = alloc((size_t)M_CLEAV_PAD * 1024 * 2);  // cleav then gates2
  u16* cleav = (u16*)uni;
  u16* gates2 = (u16*)uni;

  prep_kernel<<<2048, 256, 0, stream>>>(Wih, Whh, bih, bhh, Wihb, Whhb, bias);
  attn_pull<<<N_CLEAV / 4, 256, 0, stream>>>(feature, WgL, WgR, lostS, retS, cleav);
  // GEMM-1: 784 strips (padded), 98 per XCD, all valid
  gemm_bt<0, 512><<<784 * 8, 256, 0, stream>>>(cleav, Wihb, P, bias, 98, 784);
  lstm_step1<<<N_FRAG / 4, 256, 0, stream>>>(P, joinS, h1, c1);
  // GEMM-2: 625 valid strips, 79 per XCD (632 virtual, tail early-exits)
  gemm_bt<1, 256><<<632 * 8, 256, 0, stream>>>(h1, Whhb, gates2, nullptr, 79, 625);
  lstm_step2_attn_out<<<N_FRAG / 4, 256, 0, stream>>>(
      gates2, P, joinS, c1, h1, Wgf, Wout, bout, frag_out);
  scatter_sum<<<(N_OUT * 8 + 255) / 256, 256, 0, stream>>>(frag_out, combS, out);
}

// Round 5
// 729.927 us; speedup vs baseline: 1.5759x; 1.0229x over previous
//
#include <hip/hip_runtime.h>

typedef unsigned short u16;
typedef unsigned int u32;
typedef float f32x4 __attribute__((ext_vector_type(4)));
typedef __bf16 bf16x8 __attribute__((ext_vector_type(8)));

#define F 256
#define T_OUT 8
#define N_MONO 150000
#define N_CLEAV 100000
#define N_FRAG 80000
#define N_OUT 40000
#define M_CLEAV_PAD 100352   // 784 * 128 (98 strips per XCD * 8)

static __device__ __forceinline__ u16 f2bf(float f) {
  u32 u = __float_as_uint(f);
  u32 r = (u + 0x7FFFu + ((u >> 16) & 1u)) >> 16;
  return (u16)r;
}
static __device__ __forceinline__ float bf2f(u16 b) {
  return __uint_as_float(((u32)b) << 16);
}
static __device__ __forceinline__ float sigmoidf(float x) {
  return __frcp_rn(1.0f + __expf(-x));
}
static __device__ __forceinline__ float fast_tanh(float x) {
  return 1.0f - 2.0f * __frcp_rn(__expf(2.0f * x) + 1.0f);
}
static __device__ __forceinline__ void async_copy16(const u16* g, const u16* l) {
  __builtin_amdgcn_global_load_lds(
      (const __attribute__((address_space(1))) u32*)g,
      (__attribute__((address_space(3))) u32*)l,
      16, 0, 0);
}

// ---------------- K0: weight cast + bias sum ----------------
__global__ __launch_bounds__(256) void prep_kernel(
    const float* __restrict__ Wih, const float* __restrict__ Whh,
    const float* __restrict__ bih, const float* __restrict__ bhh,
    u16* __restrict__ Wihb, u16* __restrict__ Whhb, float* __restrict__ bias) {
  int i = blockIdx.x * 256 + threadIdx.x;
  if (i < 1024 * 512) Wihb[i] = f2bf(Wih[i]);
  if (i < 1024 * 256) Whhb[i] = f2bf(Whh[i]);
  if (i < 1024) bias[i] = bih[i] + bhh[i];
}

// ---------------- K1: attention pulls -> cleav [N_CLEAV, 512] bf16 --------
__global__ __launch_bounds__(256) void attn_pull(
    const float* __restrict__ feat, const float* __restrict__ WgL,
    const float* __restrict__ WgR, const int* __restrict__ lostS,
    const int* __restrict__ retS, u16* __restrict__ cleav) {
  int wave = threadIdx.x >> 6, lane = threadIdx.x & 63;
  int n = blockIdx.x * 4 + wave;
  if (n >= N_CLEAV) return;
  const float4 wgl = *(const float4*)(WgL + lane * 4);
  const float4 wgr = *(const float4*)(WgR + lane * 4);
  for (int sg = 0; sg < 2; ++sg) {
    const int* src = sg ? retS : lostS;
    float4 wg = sg ? wgr : wgl;
    int4 ridx = *(const int4*)(src + n * 4);
    int r[4] = {ridx.x, ridx.y, ridx.z, ridx.w};
    float4 x[4];
#pragma unroll
    for (int d = 0; d < 4; ++d)
      x[d] = *(const float4*)(feat + (size_t)r[d] * F + lane * 4);
    float logit[4];
#pragma unroll
    for (int d = 0; d < 4; ++d) {
      float p = x[d].x * wg.x + x[d].y * wg.y + x[d].z * wg.z + x[d].w * wg.w;
#pragma unroll
      for (int off = 32; off; off >>= 1) p += __shfl_xor(p, off);
      logit[d] = p;
    }
    float mx = fmaxf(fmaxf(logit[0], logit[1]), fmaxf(logit[2], logit[3]));
    float e0 = __expf(logit[0] - mx), e1 = __expf(logit[1] - mx);
    float e2 = __expf(logit[2] - mx), e3 = __expf(logit[3] - mx);
    float inv = 1.f / (e0 + e1 + e2 + e3);
    float a0 = e0 * inv, a1 = e1 * inv, a2 = e2 * inv, a3 = e3 * inv;
    float4 acc;
    acc.x = a0 * x[0].x + a1 * x[1].x + a2 * x[2].x + a3 * x[3].x;
    acc.y = a0 * x[0].y + a1 * x[1].y + a2 * x[2].y + a3 * x[3].y;
    acc.z = a0 * x[0].z + a1 * x[1].z + a2 * x[2].z + a3 * x[3].z;
    acc.w = a0 * x[0].w + a1 * x[1].w + a2 * x[2].w + a3 * x[3].w;
    u32 lo = (u32)f2bf(acc.x) | ((u32)f2bf(acc.y) << 16);
    u32 hi = (u32)f2bf(acc.z) | ((u32)f2bf(acc.w) << 16);
    *(uint2*)(cleav + (size_t)n * 512 + sg * 256 + lane * 4) = make_uint2(lo, hi);
  }
}

// ---------------- GEMM: C[M,1024] = A[M,K] * B[1024,K]^T ------------------
// bf16 MFMA 16x16x32, 128x128 tile, BK=32, TRIPLE-buffered LDS (48 KB),
// raw s_barrier + manual s_waitcnt vmcnt(4): stage(s) issued at iter s-2,
// only stage(t) must have landed at barrier(t) -> ~2 bodies of prefetch
// slack, stage(t+1)'s 4 loads stay in flight across the barrier.
// XOR swizzle on (m>>1)&3 (conflict-free), XCD-aware block remap.
// EPI==0: C = acc + bias[n]; EPI==1: C = acc.
template <int EPI, int K>
__global__ __launch_bounds__(256, 4) void gemm_bt(
    const u16* __restrict__ A, const u16* __restrict__ Bw,
    u16* __restrict__ C, const float* __restrict__ bias,
    int nper, int mstrips_valid) {
  __shared__ u16 As[3][128 * 32];
  __shared__ u16 Bs[3][128 * 32];
  const int flat = blockIdx.x;
  const int xcd = flat & 7;
  const int w = flat >> 3;
  const int mstrip = xcd * nper + (w >> 3);
  const int nstrip = w & 7;
  if (mstrip >= mstrips_valid) return;
  const int m0 = mstrip * 128;
  const int n0 = nstrip * 128;

  const int tid = threadIdx.x;
  const int lane = tid & 63;
  const int wave = tid >> 6;
  const int quad = lane >> 4;
  const int l16 = lane & 15;
  const int wm = (wave & 1) * 64;
  const int wn = (wave >> 1) * 64;

  f32x4 acc[4][4];
#pragma unroll
  for (int i = 0; i < 4; i++)
#pragma unroll
    for (int j = 0; j < 4; j++) acc[i][j] = (f32x4){0.f, 0.f, 0.f, 0.f};

  // staging: chunk c = jj*256+tid in [0,512); row = c>>2; phys chunk = c&3;
  // logical k-chunk = (c&3) ^ ((row>>1)&3) = (c&3) ^ ((c>>3)&3)
  int srow[2], skoff[2], ldsoff[2];
#pragma unroll
  for (int jj = 0; jj < 2; jj++) {
    int c = jj * 256 + tid;
    srow[jj] = c >> 2;
    skoff[jj] = ((c & 3) ^ ((c >> 3) & 3)) * 8;
    ldsoff[jj] = (jj * 256 + (tid & ~63)) * 8;  // u16 units; HW adds lane*16B
  }
  const u16* Abase = A + (size_t)m0 * K;
  const u16* Bbase = Bw + (size_t)n0 * K;

  // per WAVE: 4 global_load_lds instructions per stage (2 A + 2 B)
  auto stage = [&](int buf, int k0) {
#pragma unroll
    for (int jj = 0; jj < 2; jj++)
      async_copy16(Abase + (size_t)srow[jj] * K + k0 + skoff[jj], &As[buf][ldsoff[jj]]);
#pragma unroll
    for (int jj = 0; jj < 2; jj++)
      async_copy16(Bbase + (size_t)srow[jj] * K + k0 + skoff[jj], &Bs[buf][ldsoff[jj]]);
  };

  constexpr int nK = K / 32;
  stage(0, 0);
  stage(1, 32);
#pragma unroll
  for (int t = 0; t < nK; ++t) {
    // wait for stage(t) only: stage(t+1)'s 4 loads may remain in flight.
    // vmcnt(4): 0xF74 = lgkmcnt(15) expcnt(7) vmcnt(4); last iter vmcnt(0).
    if (t < nK - 1) __builtin_amdgcn_s_waitcnt(0xF74);
    else            __builtin_amdgcn_s_waitcnt(0xF70);
    __builtin_amdgcn_s_barrier();
    if (t + 2 < nK) stage((t + 2) % 3, (t + 2) * 32);
    const int buf = t % 3;
    bf16x8 af[4], bfr[4];
#pragma unroll
    for (int i = 0; i < 4; i++) {
      int m = wm + i * 16 + l16;
      int jp = quad ^ ((m >> 1) & 3);
      af[i] = *(const bf16x8*)&As[buf][m * 32 + jp * 8];
    }
#pragma unroll
    for (int j = 0; j < 4; j++) {
      int n = wn + j * 16 + l16;
      int jp = quad ^ ((n >> 1) & 3);
      bfr[j] = *(const bf16x8*)&Bs[buf][n * 32 + jp * 8];
    }
#pragma unroll
    for (int i = 0; i < 4; i++)
#pragma unroll
      for (int j = 0; j < 4; j++)
        acc[i][j] = __builtin_amdgcn_mfma_f32_16x16x32_bf16(af[i], bfr[j], acc[i][j], 0, 0, 0);
  }

  // epilogue: C/D layout col=lane&15, row=quad*4+reg
#pragma unroll
  for (int i = 0; i < 4; i++) {
    int mbase = m0 + wm + i * 16 + quad * 4;
#pragma unroll
    for (int j = 0; j < 4; j++) {
      int n = n0 + wn + j * 16 + l16;
      float badd = (EPI == 0) ? bias[n] : 0.f;
#pragma unroll
      for (int r = 0; r < 4; r++) {
        int m = mbase + r;
        C[(size_t)m * 1024 + n] = f2bf(acc[i][j][r] + badd);
      }
    }
  }
}

// ---------------- K3: LSTM step 1, wave-per-fragment ----------------------
__global__ __launch_bounds__(256) void lstm_step1(
    const u16* __restrict__ P, const int* __restrict__ join,
    u16* __restrict__ h1, u16* __restrict__ c1) {
  int wave = threadIdx.x >> 6, lane = threadIdx.x & 63;
  int m = blockIdx.x * 4 + wave;
  if (m >= N_FRAG) return;
  int j0 = join[2 * m];
  const u16* row = P + (size_t)j0 * 1024 + lane * 4;
  ushort4 iv = *(const ushort4*)(row);
  ushort4 gv = *(const ushort4*)(row + 512);
  ushort4 ov = *(const ushort4*)(row + 768);
  const u16* ivp = (const u16*)&iv;
  const u16* gvp = (const u16*)&gv;
  const u16* ovp = (const u16*)&ov;
  ushort4 h4, c4;
  u16* h4p = (u16*)&h4;
  u16* c4p = (u16*)&c4;
#pragma unroll
  for (int k = 0; k < 4; k++) {
    float c = sigmoidf(bf2f(ivp[k])) * fast_tanh(bf2f(gvp[k]));
    float hv = sigmoidf(bf2f(ovp[k])) * fast_tanh(c);
    h4p[k] = f2bf(hv);
    c4p[k] = f2bf(c);
  }
  *(ushort4*)(h1 + (size_t)m * 256 + lane * 4) = h4;
  *(ushort4*)(c1 + (size_t)m * 256 + lane * 4) = c4;
}

// ------- K5: LSTM step 2 + attention over {h1,h2} + output head -----------
__global__ __launch_bounds__(256) void lstm_step2_attn_out(
    const u16* __restrict__ G2, const u16* __restrict__ P,
    const int* __restrict__ join, const u16* __restrict__ c1,
    const u16* __restrict__ h1b, const float* __restrict__ Wg,
    const float* __restrict__ Wout, const float* __restrict__ bout,
    float* __restrict__ frag_out) {
  int wave = threadIdx.x >> 6, lane = threadIdx.x & 63;
  int m = blockIdx.x * 4 + wave;
  if (m >= N_FRAG) return;
  int j1 = join[2 * m + 1];
  const u16* row = G2 + (size_t)m * 1024 + lane * 4;
  const u16* prow = P + (size_t)j1 * 1024 + lane * 4;
  ushort4 iv = *(const ushort4*)(row);
  ushort4 fv = *(const ushort4*)(row + 256);
  ushort4 gv = *(const ushort4*)(row + 512);
  ushort4 ov = *(const ushort4*)(row + 768);
  ushort4 pi = *(const ushort4*)(prow);
  ushort4 pf = *(const ushort4*)(prow + 256);
  ushort4 pg = *(const ushort4*)(prow + 512);
  ushort4 po = *(const ushort4*)(prow + 768);
  ushort4 c4 = *(const ushort4*)(c1 + (size_t)m * 256 + lane * 4);
  ushort4 h4 = *(const ushort4*)(h1b + (size_t)m * 256 + lane * 4);
  float4 wg = *(const float4*)(Wg + lane * 4);
  const u16* ivp = (const u16*)&iv; const u16* pip = (const u16*)&pi;
  const u16* fvp = (const u16*)&fv; const u16* pfp = (const u16*)&pf;
  const u16* gvp = (const u16*)&gv; const u16* pgp = (const u16*)&pg;
  const u16* ovp = (const u16*)&ov; const u16* pop = (const u16*)&po;
  const u16* c4p = (const u16*)&c4;
  const u16* h4p = (const u16*)&h4;
  const float* wgp = (const float*)&wg;

  float h1v[4], h2v[4];
  float p1 = 0.f, p2 = 0.f;
#pragma unroll
  for (int k = 0; k < 4; k++) {
    float gi = bf2f(ivp[k]) + bf2f(pip[k]);
    float gf = bf2f(fvp[k]) + bf2f(pfp[k]);
    float gg = bf2f(gvp[k]) + bf2f(pgp[k]);
    float go = bf2f(ovp[k]) + bf2f(pop[k]);
    float c2 = sigmoidf(gf) * bf2f(c4p[k]) + sigmoidf(gi) * fast_tanh(gg);
    float h2 = sigmoidf(go) * fast_tanh(c2);
    h2v[k] = h2;
    h1v[k] = bf2f(h4p[k]);
    p1 += h1v[k] * wgp[k];
    p2 += h2 * wgp[k];
  }
#pragma unroll
  for (int off = 32; off; off >>= 1) {
    p1 += __shfl_xor(p1, off);
    p2 += __shfl_xor(p2, off);
  }
  float mx = fmaxf(p1, p2);
  float e1 = __expf(p1 - mx), e2 = __expf(p2 - mx);
  float inv = __frcp_rn(e1 + e2);
  float a1 = e1 * inv, a2 = e2 * inv;

  float acc[8];
#pragma unroll
  for (int t = 0; t < 8; t++) acc[t] = 0.f;
#pragma unroll
  for (int k = 0; k < 4; k++) {
    float frag = a1 * h1v[k] + a2 * h2v[k];
    int h = lane * 4 + k;
    float4 w0 = *(const float4*)(Wout + h * 8);
    float4 w1 = *(const float4*)(Wout + h * 8 + 4);
    acc[0] += frag * w0.x; acc[1] += frag * w0.y;
    acc[2] += frag * w0.z; acc[3] += frag * w0.w;
    acc[4] += frag * w1.x; acc[5] += frag * w1.y;
    acc[6] += frag * w1.z; acc[7] += frag * w1.w;
  }
#pragma unroll
  for (int off = 32; off; off >>= 1)
#pragma unroll
    for (int t = 0; t < 8; t++) acc[t] += __shfl_xor(acc[t], off);
  if (lane == 0) {
    float4 o0, o1;
    o0.x = fmaxf(acc[0] + bout[0], 0.f);
    o0.y = fmaxf(acc[1] + bout[1], 0.f);
    o0.z = fmaxf(acc[2] + bout[2], 0.f);
    o0.w = fmaxf(acc[3] + bout[3], 0.f);
    o1.x = fmaxf(acc[4] + bout[4], 0.f);
    o1.y = fmaxf(acc[5] + bout[5], 0.f);
    o1.z = fmaxf(acc[6] + bout[6], 0.f);
    o1.w = fmaxf(acc[7] + bout[7], 0.f);
    *(float4*)(frag_out + (size_t)m * 8) = o0;
    *(float4*)(frag_out + (size_t)m * 8 + 4) = o1;
  }
}

// ---------------- K6: combine scatter-sum ---------------------------------
__global__ __launch_bounds__(256) void scatter_sum(
    const float* __restrict__ frag_out, const int* __restrict__ comb,
    float* __restrict__ out) {
  int tid = blockIdx.x * 256 + threadIdx.x;
  if (tid >= N_OUT * 8) return;
  int n = tid >> 3, t = tid & 7;
  float s = 0.f;
#pragma unroll
  for (int d = 0; d < 4; d++) {
    int f = comb[n * 4 + d];
    s += frag_out[(size_t)f * 8 + t];
  }
  out[tid] = s;
}

extern "C" void kernel_launch(void* const* d_in, const int* in_sizes, int n_in,
                              void* d_out, int out_size, void* d_ws, size_t ws_size,
                              hipStream_t stream) {
  const float* feature = (const float*)d_in[0];
  const float* WgL = (const float*)d_in[1];
  const float* WgR = (const float*)d_in[2];
  const float* Wih = (const float*)d_in[3];
  const float* Whh = (const float*)d_in[4];
  const float* bih = (const float*)d_in[5];
  const float* bhh = (const float*)d_in[6];
  const float* Wgf = (const float*)d_in[7];
  const float* Wout = (const float*)d_in[8];
  const float* bout = (const float*)d_in[9];
  const int* lostS = (const int*)d_in[10];
  const int* retS = (const int*)d_in[11];
  const int* joinS = (const int*)d_in[12];
  const int* combS = (const int*)d_in[13];
  float* out = (float*)d_out;

  char* ws = (char*)d_ws;
  size_t off = 0;
  auto alloc = [&](size_t bytes) -> char* {
    char* p = ws + off;
    off = (off + bytes + 255) & ~(size_t)255;
    return p;
  };
  u16* Wihb = (u16*)alloc((size_t)1024 * 512 * 2);
  u16* Whhb = (u16*)alloc((size_t)1024 * 256 * 2);
  float* bias = (float*)alloc(1024 * 4);
  u16* P = (u16*)alloc((size_t)M_CLEAV_PAD * 1024 * 2);
  u16* h1 = (u16*)alloc((size_t)N_FRAG * 256 * 2);
  u16* c1 = (u16*)alloc((size_t)N_FRAG * 256 * 2);
  float* frag_out = (float*)alloc((size_t)N_FRAG * 8 * 4);
  char* uni = alloc((size_t)M_CLEAV_PAD * 1024 * 2);  // cleav then gates2
  u16* cleav = (u16*)uni;
  u16* gates2 = (u16*)uni;

  prep_kernel<<<2048, 256, 0, stream>>>(Wih, Whh, bih, bhh, Wihb, Whhb, bias);
  attn_pull<<<N_CLEAV / 4, 256, 0, stream>>>(feature, WgL, WgR, lostS, retS, cleav);
  // GEMM-1: 784 strips (padded), 98 per XCD, all valid
  gemm_bt<0, 512><<<784 * 8, 256, 0, stream>>>(cleav, Wihb, P, bias, 98, 784);
  lstm_step1<<<N_FRAG / 4, 256, 0, stream>>>(P, joinS, h1, c1);
  // GEMM-2: 625 valid strips, 79 per XCD (632 virtual, tail early-exits)
  gemm_bt<1, 256><<<632 * 8, 256, 0, stream>>>(h1, Whhb, gates2, nullptr, 79, 625);
  lstm_step2_attn_out<<<N_FRAG / 4, 256, 0, stream>>>(
      gates2, P, joinS, c1, h1, Wgf, Wout, bout, frag_out);
  scatter_sum<<<(N_OUT * 8 + 255) / 256, 256, 0, stream>>>(frag_out, combS, out);
}